// Round 11
// baseline (972.912 us; speedup 1.0000x reference)
//
#include <hip/hip_runtime.h>

// Problem constants (from reference)
#define NBATCH 256
#define LI 2
#define LH 150
#define LQ 10
#define HS 128
#define WSD 128
#define KIT 40
#define AOUT 5

// Plane layout: 130 rows x 132 cols of dwords, pixel (y,x) -> plane[(y+1)*LCOLS + (x+1)].
// Row 0 / row 129 = zero halos; dword col 0 = left halo; cols 129..131 = right
// zero pad. With x0 = 4*tx, a thread's 6-wide window = dwords x0..x0+5:
// b128@x0 (16B aligned) + b64@x0+4; b128 halves are the even pairs.
#define LCOLS 132
#define LROWS 130
#define PLANE (LROWS * LCOLS)      // 17160 dwords
#define LDS_DWORDS (2 * PLANE)     // 137,280 B

// d_ws layout (floats): [0..18] w_eff | [64..) payload.
//  vin_qr : payload = per-block qr planes, [block][c*4+DY][tid][4px]
//  vin_gr : payload = per-block r planes (round-10 fallback)
#define WSOFF 64
#define QR_BLOCK_DW (LQ * 4 * 1024 * 4)   // 163,840 dwords per block
#define WS_QR_BYTES ((size_t)(WSOFF + (size_t)NBATCH * QR_BLOCK_DW) * 4)  // ~168 MB
#define WS_GR_BYTES ((size_t)(WSOFF + (size_t)NBATCH * PLANE) * 4)        // ~17 MB

typedef float v2f __attribute__((ext_vector_type(2)));
#define SPLAT(K) ((v2f){(K), (K)})
#define FMA2(A, B, C) __builtin_elementwise_fma((A), (B), (C))

// ---- Prep: collapse the linear hidden layer.
__global__ void prep_weff(const float* __restrict__ h_w,
                          const float* __restrict__ h_b,
                          const float* __restrict__ r_w,
                          float* __restrict__ w_eff) {
  const int t = threadIdx.x;
  if (t < 18) {
    const int i = t / 9, k = t % 9;
    double s = 0.0;
    for (int h = 0; h < LH; ++h)
      s += (double)r_w[h] * (double)h_w[(h * LI + i) * 9 + k];
    w_eff[t] = (float)s;
  } else if (t == 18) {
    double s = 0.0;
    for (int h = 0; h < LH; ++h)
      s += (double)r_w[h] * (double)h_b[h];
    w_eff[18] = (float)s;
  }
}

// SROA RULE (rounds 1-4): local arrays only ever indexed by compile-time
// literals. VGPR WALL (rounds 2/3/6): live set must stay under ~62 dwords.
// VALU LAW (rounds 7-10): pure VALU-issue-bound at ~0.65x nominal; only
// issue-count cuts move the needle -> hoist the iteration-invariant r-conv.

// ---------- shared window-load / tap macros ----------
#define LOAD_PROW(P, R, W)                                                   \
  {                                                                          \
    const float4 b_ = *reinterpret_cast<const float4*>((P) + (R) * LCOLS);   \
    const float2 c_ = *reinterpret_cast<const float2*>((P) + (R) * LCOLS + 4); \
    W[0] = (v2f){b_.x, b_.y};                                                \
    W[1] = (v2f){b_.z, b_.w};                                                \
    W[2] = (v2f){c_.x, c_.y};                                                \
  }

#define TAPROW(KY, WARR, K0, K1, K2)                                         \
    a0 = FMA2(SPLAT(K0), WARR[KY][0], a0);                                   \
    a1 = FMA2(SPLAT(K0), WARR[KY][1], a1);                                   \
    a0.x = __builtin_fmaf((K1), WARR[KY][0].y, a0.x);                        \
    a0.y = __builtin_fmaf((K1), WARR[KY][1].x, a0.y);                        \
    a1.x = __builtin_fmaf((K1), WARR[KY][1].y, a1.x);                        \
    a1.y = __builtin_fmaf((K1), WARR[KY][2].x, a1.y);                        \
    a0 = FMA2(SPLAT(K2), WARR[KY][1], a0);                                   \
    a1 = FMA2(SPLAT(K2), WARR[KY][2], a1);

#define WIN_SHIFT2(NEXTROW)                                                  \
  {                                                                          \
    _Pragma("unroll")                                                        \
    for (int j = 0; j < 3; ++j) {                                            \
      rw[0][j] = rw[1][j]; rw[1][j] = rw[2][j];                              \
      vw[0][j] = vw[1][j]; vw[1][j] = vw[2][j];                              \
    }                                                                        \
    LOAD_PROW(rp, (NEXTROW), rw[2])                                          \
    LOAD_PROW(vp, (NEXTROW), vw[2])                                          \
  }

#define R_ROW(DY)                                                            \
  {                                                                          \
    v2f a0 = SPLAT(beff);                                                    \
    v2f a1 = a0;                                                             \
    TAPROW(0, rw, w_eff[0], w_eff[1], w_eff[2])                              \
    TAPROW(1, rw, w_eff[3], w_eff[4], w_eff[5])                              \
    TAPROW(2, rw, w_eff[6], w_eff[7], w_eff[8])                              \
    TAPROW(0, vw, w_eff[9], w_eff[10], w_eff[11])                            \
    TAPROW(1, vw, w_eff[12], w_eff[13], w_eff[14])                           \
    TAPROW(2, vw, w_eff[15], w_eff[16], w_eff[17])                           \
    racc[DY][0] = a0; racc[DY][1] = a1;                                      \
  }

// v window slot: E pairs + odd pairs (built once per load, reused x10 chans).
#define LOADV(SLOT, R)                                                       \
  {                                                                          \
    const float4 b_ = *reinterpret_cast<const float4*>(vp + (R) * LCOLS);    \
    const float2 c_ = *reinterpret_cast<const float2*>(vp + (R) * LCOLS + 4); \
    vE[SLOT][0] = (v2f){b_.x, b_.y};                                         \
    vE[SLOT][1] = (v2f){b_.z, b_.w};                                         \
    vE[SLOT][2] = (v2f){c_.x, c_.y};                                         \
    vO[SLOT][0] = (v2f){b_.y, b_.z};                                         \
    vO[SLOT][1] = (v2f){b_.w, c_.x};                                         \
  }

// v tap-row, all-pk: 6 issues (FMA form) / seeded-mul form for the first row.
#define TAP_V(SLOT, K0, K1, K2)                                              \
    a0 = FMA2(SPLAT(K0), vE[SLOT][0], a0);                                   \
    a1 = FMA2(SPLAT(K0), vE[SLOT][1], a1);                                   \
    a0 = FMA2(SPLAT(K1), vO[SLOT][0], a0);                                   \
    a1 = FMA2(SPLAT(K1), vO[SLOT][1], a1);                                   \
    a0 = FMA2(SPLAT(K2), vE[SLOT][1], a0);                                   \
    a1 = FMA2(SPLAT(K2), vE[SLOT][2], a1);

#define TAP_VS(SLOT, K0, K1, K2)                                             \
    a0 = SPLAT(K0) * vE[SLOT][0];                                            \
    a1 = SPLAT(K0) * vE[SLOT][1];                                            \
    a0 = FMA2(SPLAT(K1), vO[SLOT][0], a0);                                   \
    a1 = FMA2(SPLAT(K1), vO[SLOT][1], a1);                                   \
    a0 = FMA2(SPLAT(K2), vE[SLOT][1], a0);                                   \
    a1 = FMA2(SPLAT(K2), vE[SLOT][2], a1);

// ---------- vin_qr: VI channel = v-taps + qr (loaded, consumed at end) ----
#define VQ_CH(C_, DY, SA, SB, SC, MERGE)                                     \
  {                                                                          \
    const float* wc = w_in + (C_) * 9;                                       \
    const float4 qf = qr4[((C_) * 4 + (DY)) * 1024 + tid];                   \
    v2f a0, a1;                                                              \
    TAP_VS(SA, wc[0], wc[1], wc[2])                                          \
    TAP_V(SB, wc[3], wc[4], wc[5])                                           \
    TAP_V(SC, wc[6], wc[7], wc[8])                                           \
    a0 += (v2f){qf.x, qf.y};                                                 \
    a1 += (v2f){qf.z, qf.w};                                                 \
    MERGE                                                                    \
  }

#define VI_OUT_Q(DY, SA, SB, SC)                                             \
  {                                                                          \
    v2f o0, o1;                                                              \
    VQ_CH(0, DY, SA, SB, SC, o0 = a0; o1 = a1;)                              \
    _Pragma("unroll 2")                                                      \
    for (int c = 1; c < LQ; ++c) {                                           \
      VQ_CH(c, DY, SA, SB, SC,                                               \
            o0 = __builtin_elementwise_max(o0, a0);                          \
            o1 = __builtin_elementwise_max(o1, a1);)                         \
    }                                                                        \
    float* w_ = wr + (DY) * LCOLS;                                           \
    w_[1] = o0.x; w_[2] = o0.y; w_[3] = o1.x; w_[4] = o1.y;                  \
  }

// ---------- vin_qr prologue: r windows with E+O pairs, all-pk r-conv ----
#define LOADR2(SLOT, R)                                                      \
  {                                                                          \
    const float4 b_ = *reinterpret_cast<const float4*>(rp + (R) * LCOLS);    \
    const float2 c_ = *reinterpret_cast<const float2*>(rp + (R) * LCOLS + 4); \
    rE[SLOT][0] = (v2f){b_.x, b_.y};                                         \
    rE[SLOT][1] = (v2f){b_.z, b_.w};                                         \
    rE[SLOT][2] = (v2f){c_.x, c_.y};                                         \
    rO[SLOT][0] = (v2f){b_.y, b_.z};                                         \
    rO[SLOT][1] = (v2f){b_.w, c_.x};                                         \
  }

#define QTAP(SLOT, K0, K1, K2)                                               \
    a0 = FMA2(SPLAT(K0), rE[SLOT][0], a0);                                   \
    a1 = FMA2(SPLAT(K0), rE[SLOT][1], a1);                                   \
    a0 = FMA2(SPLAT(K1), rO[SLOT][0], a0);                                   \
    a1 = FMA2(SPLAT(K1), rO[SLOT][1], a1);                                   \
    a0 = FMA2(SPLAT(K2), rE[SLOT][1], a0);                                   \
    a1 = FMA2(SPLAT(K2), rE[SLOT][2], a1);

#define QTAP_S(SLOT, K0, K1, K2)                                             \
    a0 = SPLAT(K0) * rE[SLOT][0];                                            \
    a1 = SPLAT(K0) * rE[SLOT][1];                                            \
    a0 = FMA2(SPLAT(K1), rO[SLOT][0], a0);                                   \
    a1 = FMA2(SPLAT(K1), rO[SLOT][1], a1);                                   \
    a0 = FMA2(SPLAT(K2), rE[SLOT][1], a0);                                   \
    a1 = FMA2(SPLAT(K2), rE[SLOT][2], a1);

#define QR_ROW(DY, SA, SB, SC)                                               \
  {                                                                          \
    _Pragma("unroll 2")                                                      \
    for (int c = 0; c < LQ; ++c) {                                           \
      const float* qc = q_w + c * 9;                                         \
      v2f a0, a1;                                                            \
      QTAP_S(SA, qc[0], qc[1], qc[2])                                        \
      QTAP(SB, qc[3], qc[4], qc[5])                                          \
      QTAP(SC, qc[6], qc[7], qc[8])                                          \
      qr4[(c * 4 + (DY)) * 1024 + tid] =                                     \
          make_float4(a0.x, a0.y, a1.x, a1.y);                               \
    }                                                                        \
  }

// ---------------- Primary kernel: qr precomputed (L3-resident, same-thread
// readback), v ping-pong in LDS, one barrier per VI iteration. ------------
__global__ __launch_bounds__(1024)
__attribute__((amdgpu_waves_per_eu(4, 4)))
void vin_qr(const float* __restrict__ input,
            const int* __restrict__ coords,
            const float* __restrict__ q_w,
            const float* __restrict__ w_in,
            const float* __restrict__ fc_w,
            float* __restrict__ ws,
            float* __restrict__ out) {
  extern __shared__ float lds[];
  float* pA = lds;          // stages ch0; r plane during qr-phase; v plane A
  float* pB = lds + PLANE;  // stages ch1; then v plane B (it=0 reads here)
  const float* w_eff = ws;  // 19 floats
  float4* qr4 = reinterpret_cast<float4*>(ws + WSOFF) +
                (size_t)blockIdx.x * (QR_BLOCK_DW / 4);

  const int b = blockIdx.x;
  const int tid = threadIdx.x;
  const int ty = tid >> 5;              // 0..31
  const int tx = tid & 31;              // 0..31
  const int y0 = ty << 2;               // output rows y0..y0+3
  const int x0 = tx << 2;               // output cols x0..x0+3
  const int nb_base = y0 * LCOLS + x0;  // window base
  const int wrow0 = (y0 + 1) * LCOLS + x0;  // write row base (dwords +1..+4)

  // zero LDS planes (halos must be 0; both planes serve as v later)
  for (int i = tid; i < LDS_DWORDS; i += 1024) lds[i] = 0.0f;
  __syncthreads();

  // stage input: ch0 -> pA interior, ch1 -> pB interior (+1 dword col shift)
  const float* in0 = input + (size_t)b * (LI * HS * WSD);
  const float* in1 = in0 + HS * WSD;
  {
    const float4* in40 = (const float4*)in0;
    const float4* in41 = (const float4*)in1;
    for (int i = tid; i < HS * WSD / 4; i += 1024) {
      const int y = i >> 5, x4 = (i & 31) << 2;
      const float4 a = in40[i];
      const float4 c = in41[i];
      float* r_ = pA + (y + 1) * LCOLS + x4;
      float* v_ = pB + (y + 1) * LCOLS + x4;
      r_[1] = a.x; r_[2] = a.y; r_[3] = a.z; r_[4] = a.w;
      v_[1] = c.x; v_[2] = c.y; v_[3] = c.z; v_[4] = c.w;
    }
  }
  __syncthreads();

  // ---- r = conv(input, W_eff, pad=1) + b_eff ----
  {
    const float* rp = pA + nb_base;
    const float* vp = pB + nb_base;
    v2f rw[3][3], vw[3][3], racc[4][2];
    LOAD_PROW(rp, 0, rw[0]) LOAD_PROW(rp, 1, rw[1]) LOAD_PROW(rp, 2, rw[2])
    LOAD_PROW(vp, 0, vw[0]) LOAD_PROW(vp, 1, vw[1]) LOAD_PROW(vp, 2, vw[2])
    const float beff = w_eff[18];
    R_ROW(0) WIN_SHIFT2(3) R_ROW(1) WIN_SHIFT2(4) R_ROW(2) WIN_SHIFT2(5) R_ROW(3)
    __syncthreads();  // all staged-input reads done
    // pA <- r (read by qr-phase), pB <- 0 (v starts at zero; it=0 reads pB)
#pragma unroll
    for (int dy = 0; dy < 4; ++dy) {
      float* r_ = pA + wrow0 + dy * LCOLS;
      float* v_ = pB + wrow0 + dy * LCOLS;
      r_[1] = racc[dy][0].x; r_[2] = racc[dy][0].y;
      r_[3] = racc[dy][1].x; r_[4] = racc[dy][1].y;
      v_[1] = 0.0f; v_[2] = 0.0f; v_[3] = 0.0f; v_[4] = 0.0f;
    }
  }
  __syncthreads();  // r plane visible to qr-phase windows

  // ---- qr[c] = conv(r, q_w[c]) for the thread's 16 px -> global qr ----
  {
    const float* rp = pA + nb_base;
    v2f rE[3][3], rO[3][2];
    LOADR2(0, 0) LOADR2(1, 1) LOADR2(2, 2)
    QR_ROW(0, 0, 1, 2)
    LOADR2(0, 3) QR_ROW(1, 1, 2, 0)
    LOADR2(1, 4) QR_ROW(2, 2, 0, 1)
    LOADR2(2, 5) QR_ROW(3, 0, 1, 2)
  }
  __syncthreads();  // qr-phase r reads done (it=0 overwrites pA); the
                    // barrier's vmcnt drain also lands the qr stores in L2

  // ---- 40 VI iterations, ONE barrier each ----
  // it even: read pB, write pA; it odd: read pA, write pB -> final v in pB.
  // it=0 (v==0) yields exactly v0 = max_c qr[c].
#pragma unroll 1
  for (int it = 0; it < KIT; ++it) {
    const float* vp = lds + ((it & 1) ? 0 : PLANE) + nb_base;
    float* wr = lds + ((it & 1) ? PLANE : 0) + wrow0;
    v2f vE[3][3], vO[3][2];
    LOADV(0, 0) LOADV(1, 1) LOADV(2, 2)
    VI_OUT_Q(0, 0, 1, 2)
    LOADV(0, 3) VI_OUT_Q(1, 1, 2, 0)
    LOADV(1, 4) VI_OUT_Q(2, 2, 0, 1)
    LOADV(2, 5) VI_OUT_Q(3, 0, 1, 2)
    __syncthreads();  // write-plane visible; next iter swaps planes
  }

  // ---- epilogue: q at (sx,sy) = qr + conv(v,w); logits = fc_w @ q ----
  if (tid == 0) {
    const int sx = coords[b * 4 + 0];
    const int sy = coords[b * 4 + 1];
    const float* qrf = reinterpret_cast<const float*>(qr4);
    const int tidp = ((sx >> 2) << 5) | (sy >> 2);  // owner thread of (sx,sy)
    const int dyp = sx & 3, pxp = sy & 3;
    float qv[LQ];
#pragma unroll 1
    for (int c = 0; c < LQ; ++c) {
      float s = qrf[((c * 4 + dyp) * 1024 + tidp) * 4 + pxp];
#pragma unroll
      for (int kk = 0; kk < 9; ++kk) {
        const int ky = kk / 3, kx = kk % 3;
        s = __builtin_fmaf(w_in[c * 9 + kk],
                           pB[(sx + ky) * LCOLS + (sy + kx)], s);
      }
      qv[c] = s;
    }
#pragma unroll 1
    for (int a = 0; a < AOUT; ++a) {
      float s = 0.0f;
#pragma unroll
      for (int c = 0; c < LQ; ++c)
        s = __builtin_fmaf(fc_w[a * LQ + c], qv[c], s);
      out[b * AOUT + a] = s;
    }
  }
}

// ---------------- Fallback: round-10 kernel (proven 642 us), used if ws
// can't hold the qr planes (needs only ~17 MB). ----------------
#define LOADR(SLOT, R)                                                       \
  {                                                                          \
    const float4 b_ = *reinterpret_cast<const float4*>(rp + (R) * LCOLS);    \
    const float2 c_ = *reinterpret_cast<const float2*>(rp + (R) * LCOLS + 4); \
    rP[SLOT][0] = (v2f){b_.x, b_.y};                                         \
    rP[SLOT][1] = (v2f){b_.z, b_.w};                                         \
    rP[SLOT][2] = (v2f){c_.x, c_.y};                                         \
  }

#define TAP_R(SLOT, K0, K1, K2)                                              \
    a0 = FMA2(SPLAT(K0), rP[SLOT][0], a0);                                   \
    a1 = FMA2(SPLAT(K0), rP[SLOT][1], a1);                                   \
    a0.x = __builtin_fmaf((K1), rP[SLOT][0].y, a0.x);                        \
    a0.y = __builtin_fmaf((K1), rP[SLOT][1].x, a0.y);                        \
    a1.x = __builtin_fmaf((K1), rP[SLOT][1].y, a1.x);                        \
    a1.y = __builtin_fmaf((K1), rP[SLOT][2].x, a1.y);                        \
    a0 = FMA2(SPLAT(K2), rP[SLOT][1], a0);                                   \
    a1 = FMA2(SPLAT(K2), rP[SLOT][2], a1);

#define VI_CH3(QC, WC, SA, SB, SC, MERGE)                                    \
  {                                                                          \
    const float* qc = (QC);                                                  \
    const float* wc = (WC);                                                  \
    v2f a0 = SPLAT(qc[0]) * rP[SA][0];                                       \
    v2f a1 = SPLAT(qc[0]) * rP[SA][1];                                       \
    a0.x = __builtin_fmaf(qc[1], rP[SA][0].y, a0.x);                         \
    a0.y = __builtin_fmaf(qc[1], rP[SA][1].x, a0.y);                         \
    a1.x = __builtin_fmaf(qc[1], rP[SA][1].y, a1.x);                         \
    a1.y = __builtin_fmaf(qc[1], rP[SA][2].x, a1.y);                         \
    a0 = FMA2(SPLAT(qc[2]), rP[SA][1], a0);                                  \
    a1 = FMA2(SPLAT(qc[2]), rP[SA][2], a1);                                  \
    TAP_R(SB, qc[3], qc[4], qc[5])                                           \
    TAP_R(SC, qc[6], qc[7], qc[8])                                           \
    TAP_V(SA, wc[0], wc[1], wc[2])                                           \
    TAP_V(SB, wc[3], wc[4], wc[5])                                           \
    TAP_V(SC, wc[6], wc[7], wc[8])                                           \
    MERGE                                                                    \
  }

#define VI_OUT(DY, SA, SB, SC)                                               \
  {                                                                          \
    v2f o0, o1;                                                              \
    VI_CH3(q_w, w_in, SA, SB, SC, o0 = a0; o1 = a1;)                         \
    _Pragma("unroll 3")                                                      \
    for (int c = 1; c < LQ; ++c) {                                           \
      VI_CH3(q_w + c * 9, w_in + c * 9, SA, SB, SC,                          \
             o0 = __builtin_elementwise_max(o0, a0);                         \
             o1 = __builtin_elementwise_max(o1, a1);)                        \
    }                                                                        \
    float* w_ = wr + (DY) * LCOLS;                                           \
    w_[1] = o0.x; w_[2] = o0.y; w_[3] = o1.x; w_[4] = o1.y;                  \
  }

__global__ __launch_bounds__(1024)
__attribute__((amdgpu_waves_per_eu(4, 4)))
void vin_gr(const float* __restrict__ input,
            const int* __restrict__ coords,
            const float* __restrict__ q_w,
            const float* __restrict__ w_in,
            const float* __restrict__ fc_w,
            float* __restrict__ ws,
            float* __restrict__ out) {
  extern __shared__ float lds[];
  float* pA = lds;
  float* pB = lds + PLANE;
  const float* w_eff = ws;
  float* g_r = ws + WSOFF + (size_t)blockIdx.x * PLANE;

  const int b = blockIdx.x;
  const int tid = threadIdx.x;
  const int ty = tid >> 5;
  const int tx = tid & 31;
  const int y0 = ty << 2;
  const int x0 = tx << 2;
  const int nb_base = y0 * LCOLS + x0;
  const int wrow0 = (y0 + 1) * LCOLS + x0;

  for (int i = tid; i < LDS_DWORDS; i += 1024) lds[i] = 0.0f;
  if (tid < LCOLS) { g_r[tid] = 0.0f; g_r[129 * LCOLS + tid] = 0.0f; }
  if (tid >= 256 && tid < 384) {
    const int row = tid - 255;
    g_r[row * LCOLS + 0] = 0.0f;
    g_r[row * LCOLS + 129] = 0.0f;
    g_r[row * LCOLS + 130] = 0.0f;
    g_r[row * LCOLS + 131] = 0.0f;
  }
  __syncthreads();

  const float* in0 = input + (size_t)b * (LI * HS * WSD);
  const float* in1 = in0 + HS * WSD;
  {
    const float4* in40 = (const float4*)in0;
    const float4* in41 = (const float4*)in1;
    for (int i = tid; i < HS * WSD / 4; i += 1024) {
      const int y = i >> 5, x4 = (i & 31) << 2;
      const float4 a = in40[i];
      const float4 c = in41[i];
      float* r_ = pA + (y + 1) * LCOLS + x4;
      float* v_ = pB + (y + 1) * LCOLS + x4;
      r_[1] = a.x; r_[2] = a.y; r_[3] = a.z; r_[4] = a.w;
      v_[1] = c.x; v_[2] = c.y; v_[3] = c.z; v_[4] = c.w;
    }
  }
  __syncthreads();

  {
    const float* rp = pA + nb_base;
    const float* vp = pB + nb_base;
    v2f rw[3][3], vw[3][3], racc[4][2];
    LOAD_PROW(rp, 0, rw[0]) LOAD_PROW(rp, 1, rw[1]) LOAD_PROW(rp, 2, rw[2])
    LOAD_PROW(vp, 0, vw[0]) LOAD_PROW(vp, 1, vw[1]) LOAD_PROW(vp, 2, vw[2])
    const float beff = w_eff[18];
    R_ROW(0) WIN_SHIFT2(3) R_ROW(1) WIN_SHIFT2(4) R_ROW(2) WIN_SHIFT2(5) R_ROW(3)
    __syncthreads();
#pragma unroll
    for (int dy = 0; dy < 4; ++dy) {
      float* g_ = g_r + wrow0 + dy * LCOLS;
      float* v_ = pA + wrow0 + dy * LCOLS;
      g_[1] = racc[dy][0].x; g_[2] = racc[dy][0].y;
      g_[3] = racc[dy][1].x; g_[4] = racc[dy][1].y;
      v_[1] = 0.0f; v_[2] = 0.0f; v_[3] = 0.0f; v_[4] = 0.0f;
    }
  }
  __syncthreads();

  const float* grp = g_r + nb_base;
#pragma unroll 1
  for (int it = 0; it < KIT; ++it) {
    const float* vp = lds + ((it & 1) ? PLANE : 0) + nb_base;
    float* wr = lds + ((it & 1) ? 0 : PLANE) + wrow0;
    const float* rp = grp;
    v2f rP[3][3], vE[3][3], vO[3][2];
    LOADR(0, 0) LOADR(1, 1) LOADR(2, 2)
    LOADV(0, 0) LOADV(1, 1) LOADV(2, 2)
    VI_OUT(0, 0, 1, 2)
    LOADR(0, 3) LOADV(0, 3)
    VI_OUT(1, 1, 2, 0)
    LOADR(1, 4) LOADV(1, 4)
    VI_OUT(2, 2, 0, 1)
    LOADR(2, 5) LOADV(2, 5)
    VI_OUT(3, 0, 1, 2)
    __syncthreads();
  }

  if (tid == 0) {
    const int sx = coords[b * 4 + 0];
    const int sy = coords[b * 4 + 1];
    float qv[LQ];
#pragma unroll 1
    for (int c = 0; c < LQ; ++c) {
      float s = 0.0f;
#pragma unroll
      for (int kk = 0; kk < 9; ++kk) {
        const int ky = kk / 3, kx = kk % 3;
        const int off = (sx + ky) * LCOLS + (sy + kx);
        s = __builtin_fmaf(q_w[c * 9 + kk], g_r[off],
            __builtin_fmaf(w_in[c * 9 + kk], pA[off], s));
      }
      qv[c] = s;
    }
#pragma unroll 1
    for (int a = 0; a < AOUT; ++a) {
      float s = 0.0f;
#pragma unroll
      for (int c = 0; c < LQ; ++c)
        s = __builtin_fmaf(fc_w[a * LQ + c], qv[c], s);
      out[b * AOUT + a] = s;
    }
  }
}

extern "C" void kernel_launch(void* const* d_in, const int* in_sizes, int n_in,
                              void* d_out, int out_size, void* d_ws, size_t ws_size,
                              hipStream_t stream) {
  const float* input = (const float*)d_in[0];   // (B, 2, 128, 128)
  const int*   coords = (const int*)d_in[1];    // (B, 4)
  const float* h_w = (const float*)d_in[2];     // (150, 2, 3, 3)
  const float* h_b = (const float*)d_in[3];     // (150,)
  const float* r_w = (const float*)d_in[4];     // (1, 150, 1, 1)
  const float* q_w = (const float*)d_in[5];     // (10, 1, 3, 3)
  const float* w_in = (const float*)d_in[6];    // (10, 1, 3, 3)
  const float* fc_w = (const float*)d_in[7];    // (5, 10)
  float* out = (float*)d_out;                   // (B, 5)
  float* ws = (float*)d_ws;

  const size_t smem = (size_t)LDS_DWORDS * sizeof(float);  // 137,280 B

  prep_weff<<<1, 64, 0, stream>>>(h_w, h_b, r_w, ws);

  if (ws_size >= WS_QR_BYTES) {
    hipFuncSetAttribute(reinterpret_cast<const void*>(vin_qr),
                        hipFuncAttributeMaxDynamicSharedMemorySize, (int)smem);
    vin_qr<<<NBATCH, 1024, smem, stream>>>(input, coords, q_w, w_in, fc_w, ws, out);
  } else {
    hipFuncSetAttribute(reinterpret_cast<const void*>(vin_gr),
                        hipFuncAttributeMaxDynamicSharedMemorySize, (int)smem);
    vin_gr<<<NBATCH, 1024, smem, stream>>>(input, coords, q_w, w_in, fc_w, ws, out);
  }
}

// Round 12
// 919.802 us; speedup vs baseline: 1.0577x; 1.0577x over previous
//
#include <hip/hip_runtime.h>

// Problem constants (from reference)
#define NBATCH 256
#define LI 2
#define LH 150
#define LQ 10
#define HS 128
#define WSD 128
#define KIT 40
#define AOUT 5

// Plane layout: 130 rows x 132 cols of dwords, pixel (y,x) -> plane[(y+1)*LCOLS + (x+1)].
// Row 0 / row 129 = zero halos; dword col 0 = left halo; cols 129..131 = right
// zero pad. With x0 = 4*tx, a thread's 6-wide window = dwords x0..x0+5:
// b128@x0 (16B aligned) + b64@x0+4; b128 halves are the even pairs.
#define LCOLS 132
#define LROWS 130
#define PLANE (LROWS * LCOLS)      // 17160 dwords
#define LDS_DWORDS (2 * PLANE)     // 137,280 B

// d_ws layout (floats): [0..18] w_eff | [64..) payload.
//  vin_qrh: payload = per-block fp16 qr, h4[(c*4+dy)*1024 + tid]
//  vin_gr : payload = per-block r planes (round-10 fallback)
#define WSOFF 64
#define QRH_BLOCK_H4 (LQ * 4 * 1024)  // 40960 h4 (8 B each) per block
#define WS_QRH_BYTES ((size_t)WSOFF * 4 + (size_t)NBATCH * QRH_BLOCK_H4 * 8)  // ~84 MB
#define WS_GR_BYTES ((size_t)(WSOFF + (size_t)NBATCH * PLANE) * 4)            // ~17 MB

typedef float v2f __attribute__((ext_vector_type(2)));
typedef _Float16 h4 __attribute__((ext_vector_type(4)));
#define SPLAT(K) ((v2f){(K), (K)})
#define FMA2(A, B, C) __builtin_elementwise_fma((A), (B), (C))

// ---- Prep: collapse the linear hidden layer.
__global__ void prep_weff(const float* __restrict__ h_w,
                          const float* __restrict__ h_b,
                          const float* __restrict__ r_w,
                          float* __restrict__ w_eff) {
  const int t = threadIdx.x;
  if (t < 18) {
    const int i = t / 9, k = t % 9;
    double s = 0.0;
    for (int h = 0; h < LH; ++h)
      s += (double)r_w[h] * (double)h_w[(h * LI + i) * 9 + k];
    w_eff[t] = (float)s;
  } else if (t == 18) {
    double s = 0.0;
    for (int h = 0; h < LH; ++h)
      s += (double)r_w[h] * (double)h_b[h];
    w_eff[18] = (float)s;
  }
}

// SROA RULE (r1-4): local arrays only ever literal-indexed. VGPR WALL
// (r2/3/6): live set must stay under ~62 dwords. VALU LAW (r7-10): pure
// VALU-issue-bound; only issue cuts count. MEMORY LAW (r11): fp32 qr
// (168 MB) is only ~50% L3-resident -> short load-use distance stalls
// the wave. Fix: fp16 qr (84 MB, L3-fits) + one-row-ahead prefetch.

// ---------- shared window-load / tap macros ----------
#define LOAD_PROW(P, R, W)                                                   \
  {                                                                          \
    const float4 b_ = *reinterpret_cast<const float4*>((P) + (R) * LCOLS);   \
    const float2 c_ = *reinterpret_cast<const float2*>((P) + (R) * LCOLS + 4); \
    W[0] = (v2f){b_.x, b_.y};                                                \
    W[1] = (v2f){b_.z, b_.w};                                                \
    W[2] = (v2f){c_.x, c_.y};                                                \
  }

#define TAPROW(KY, WARR, K0, K1, K2)                                         \
    a0 = FMA2(SPLAT(K0), WARR[KY][0], a0);                                   \
    a1 = FMA2(SPLAT(K0), WARR[KY][1], a1);                                   \
    a0.x = __builtin_fmaf((K1), WARR[KY][0].y, a0.x);                        \
    a0.y = __builtin_fmaf((K1), WARR[KY][1].x, a0.y);                        \
    a1.x = __builtin_fmaf((K1), WARR[KY][1].y, a1.x);                        \
    a1.y = __builtin_fmaf((K1), WARR[KY][2].x, a1.y);                        \
    a0 = FMA2(SPLAT(K2), WARR[KY][1], a0);                                   \
    a1 = FMA2(SPLAT(K2), WARR[KY][2], a1);

#define WIN_SHIFT2(NEXTROW)                                                  \
  {                                                                          \
    _Pragma("unroll")                                                        \
    for (int j = 0; j < 3; ++j) {                                            \
      rw[0][j] = rw[1][j]; rw[1][j] = rw[2][j];                              \
      vw[0][j] = vw[1][j]; vw[1][j] = vw[2][j];                              \
    }                                                                        \
    LOAD_PROW(rp, (NEXTROW), rw[2])                                          \
    LOAD_PROW(vp, (NEXTROW), vw[2])                                          \
  }

#define R_ROW(DY)                                                            \
  {                                                                          \
    v2f a0 = SPLAT(beff);                                                    \
    v2f a1 = a0;                                                             \
    TAPROW(0, rw, w_eff[0], w_eff[1], w_eff[2])                              \
    TAPROW(1, rw, w_eff[3], w_eff[4], w_eff[5])                              \
    TAPROW(2, rw, w_eff[6], w_eff[7], w_eff[8])                              \
    TAPROW(0, vw, w_eff[9], w_eff[10], w_eff[11])                            \
    TAPROW(1, vw, w_eff[12], w_eff[13], w_eff[14])                           \
    TAPROW(2, vw, w_eff[15], w_eff[16], w_eff[17])                           \
    racc[DY][0] = a0; racc[DY][1] = a1;                                      \
  }

// v window slot: E pairs + odd pairs (built once per load, reused x10 chans).
#define LOADV(SLOT, R)                                                       \
  {                                                                          \
    const float4 b_ = *reinterpret_cast<const float4*>(vp + (R) * LCOLS);    \
    const float2 c_ = *reinterpret_cast<const float2*>(vp + (R) * LCOLS + 4); \
    vE[SLOT][0] = (v2f){b_.x, b_.y};                                         \
    vE[SLOT][1] = (v2f){b_.z, b_.w};                                         \
    vE[SLOT][2] = (v2f){c_.x, c_.y};                                         \
    vO[SLOT][0] = (v2f){b_.y, b_.z};                                         \
    vO[SLOT][1] = (v2f){b_.w, c_.x};                                         \
  }

#define TAP_V(SLOT, K0, K1, K2)                                              \
    a0 = FMA2(SPLAT(K0), vE[SLOT][0], a0);                                   \
    a1 = FMA2(SPLAT(K0), vE[SLOT][1], a1);                                   \
    a0 = FMA2(SPLAT(K1), vO[SLOT][0], a0);                                   \
    a1 = FMA2(SPLAT(K1), vO[SLOT][1], a1);                                   \
    a0 = FMA2(SPLAT(K2), vE[SLOT][1], a0);                                   \
    a1 = FMA2(SPLAT(K2), vE[SLOT][2], a1);

#define TAP_VS(SLOT, K0, K1, K2)                                             \
    a0 = SPLAT(K0) * vE[SLOT][0];                                            \
    a1 = SPLAT(K0) * vE[SLOT][1];                                            \
    a0 = FMA2(SPLAT(K1), vO[SLOT][0], a0);                                   \
    a1 = FMA2(SPLAT(K1), vO[SLOT][1], a1);                                   \
    a0 = FMA2(SPLAT(K2), vE[SLOT][1], a0);                                   \
    a1 = FMA2(SPLAT(K2), vE[SLOT][2], a1);

// r windows with E+O pairs (qr prologue), all-pk.
#define LOADR2(SLOT, R)                                                      \
  {                                                                          \
    const float4 b_ = *reinterpret_cast<const float4*>(rp + (R) * LCOLS);    \
    const float2 c_ = *reinterpret_cast<const float2*>(rp + (R) * LCOLS + 4); \
    rE[SLOT][0] = (v2f){b_.x, b_.y};                                         \
    rE[SLOT][1] = (v2f){b_.z, b_.w};                                         \
    rE[SLOT][2] = (v2f){c_.x, c_.y};                                         \
    rO[SLOT][0] = (v2f){b_.y, b_.z};                                         \
    rO[SLOT][1] = (v2f){b_.w, c_.x};                                         \
  }

#define QTAP(SLOT, K0, K1, K2)                                               \
    a0 = FMA2(SPLAT(K0), rE[SLOT][0], a0);                                   \
    a1 = FMA2(SPLAT(K0), rE[SLOT][1], a1);                                   \
    a0 = FMA2(SPLAT(K1), rO[SLOT][0], a0);                                   \
    a1 = FMA2(SPLAT(K1), rO[SLOT][1], a1);                                   \
    a0 = FMA2(SPLAT(K2), rE[SLOT][1], a0);                                   \
    a1 = FMA2(SPLAT(K2), rE[SLOT][2], a1);

#define QTAP_S(SLOT, K0, K1, K2)                                             \
    a0 = SPLAT(K0) * rE[SLOT][0];                                            \
    a1 = SPLAT(K0) * rE[SLOT][1];                                            \
    a0 = FMA2(SPLAT(K1), rO[SLOT][0], a0);                                   \
    a1 = FMA2(SPLAT(K1), rO[SLOT][1], a1);                                   \
    a0 = FMA2(SPLAT(K2), rE[SLOT][1], a0);                                   \
    a1 = FMA2(SPLAT(K2), rE[SLOT][2], a1);

// qr prologue row -> fp16x4 store (c only indexes GLOBAL memory: SROA-safe).
#define QRH_ROW(DY, SA, SB, SC)                                              \
  {                                                                          \
    _Pragma("unroll 2")                                                      \
    for (int c = 0; c < LQ; ++c) {                                           \
      const float* qc = q_w + c * 9;                                         \
      v2f a0, a1;                                                            \
      QTAP_S(SA, qc[0], qc[1], qc[2])                                        \
      QTAP(SB, qc[3], qc[4], qc[5])                                          \
      QTAP(SC, qc[6], qc[7], qc[8])                                          \
      h4 h_;                                                                 \
      h_.x = (_Float16)a0.x; h_.y = (_Float16)a0.y;                          \
      h_.z = (_Float16)a1.x; h_.w = (_Float16)a1.y;                          \
      qrh[(c * 4 + (DY)) * 1024 + tid] = h_;                                 \
    }                                                                        \
  }

// VI channel: v-taps + fp16 qr (consumed at END of the chain, loaded one
// row earlier), then prefetch the same slot for row DYN.
#define VQ_CH2(C_, DYN, SA, SB, SC, MERGE)                                   \
  {                                                                          \
    const float* wc = w_in + (C_) * 9;                                       \
    v2f a0, a1;                                                              \
    TAP_VS(SA, wc[0], wc[1], wc[2])                                          \
    TAP_V(SB, wc[3], wc[4], wc[5])                                           \
    TAP_V(SC, wc[6], wc[7], wc[8])                                           \
    a0 += (v2f){(float)qb[C_].x, (float)qb[C_].y};                           \
    a1 += (v2f){(float)qb[C_].z, (float)qb[C_].w};                           \
    qb[C_] = qrh[((C_) * 4 + (DYN)) * 1024 + tid];  /* prefetch row DYN */   \
    MERGE                                                                    \
  }

#define MAXM o0 = __builtin_elementwise_max(o0, a0);                         \
             o1 = __builtin_elementwise_max(o1, a1);

// One output row: fully hand-unrolled channels (qb needs literal indices).
#define VI_OUT_QH(DY, DYN, SA, SB, SC)                                       \
  {                                                                          \
    v2f o0, o1;                                                              \
    VQ_CH2(0, DYN, SA, SB, SC, o0 = a0; o1 = a1;)                            \
    VQ_CH2(1, DYN, SA, SB, SC, MAXM)                                         \
    VQ_CH2(2, DYN, SA, SB, SC, MAXM)                                         \
    VQ_CH2(3, DYN, SA, SB, SC, MAXM)                                         \
    VQ_CH2(4, DYN, SA, SB, SC, MAXM)                                         \
    VQ_CH2(5, DYN, SA, SB, SC, MAXM)                                         \
    VQ_CH2(6, DYN, SA, SB, SC, MAXM)                                         \
    VQ_CH2(7, DYN, SA, SB, SC, MAXM)                                         \
    VQ_CH2(8, DYN, SA, SB, SC, MAXM)                                         \
    VQ_CH2(9, DYN, SA, SB, SC, MAXM)                                         \
    float* w_ = wr + (DY) * LCOLS;                                           \
    w_[1] = o0.x; w_[2] = o0.y; w_[3] = o1.x; w_[4] = o1.y;                  \
  }

#define PREQ(C_) qb[C_] = qrh[(C_) * 4 * 1024 + tid];

// ---------------- Primary: fp16 qr (L3-resident) + one-row-ahead prefetch,
// v ping-pong in LDS, one barrier per VI iteration. ----------------
__global__ __launch_bounds__(1024)
__attribute__((amdgpu_waves_per_eu(4, 4)))
void vin_qrh(const float* __restrict__ input,
             const int* __restrict__ coords,
             const float* __restrict__ q_w,
             const float* __restrict__ w_in,
             const float* __restrict__ fc_w,
             float* __restrict__ ws,
             float* __restrict__ out) {
  extern __shared__ float lds[];
  float* pA = lds;          // stages ch0; r plane during qr-phase; v plane A
  float* pB = lds + PLANE;  // stages ch1; then v plane B (it=0 reads here)
  const float* w_eff = ws;  // 19 floats
  h4* qrh = reinterpret_cast<h4*>(ws + WSOFF) +
            (size_t)blockIdx.x * QRH_BLOCK_H4;

  const int b = blockIdx.x;
  const int tid = threadIdx.x;
  const int ty = tid >> 5;              // 0..31
  const int tx = tid & 31;              // 0..31
  const int y0 = ty << 2;               // output rows y0..y0+3
  const int x0 = tx << 2;               // output cols x0..x0+3
  const int nb_base = y0 * LCOLS + x0;  // window base
  const int wrow0 = (y0 + 1) * LCOLS + x0;  // write row base (dwords +1..+4)

  // zero LDS planes (halos must be 0; both planes serve as v later)
  for (int i = tid; i < LDS_DWORDS; i += 1024) lds[i] = 0.0f;
  __syncthreads();

  // stage input: ch0 -> pA interior, ch1 -> pB interior (+1 dword col shift)
  const float* in0 = input + (size_t)b * (LI * HS * WSD);
  const float* in1 = in0 + HS * WSD;
  {
    const float4* in40 = (const float4*)in0;
    const float4* in41 = (const float4*)in1;
    for (int i = tid; i < HS * WSD / 4; i += 1024) {
      const int y = i >> 5, x4 = (i & 31) << 2;
      const float4 a = in40[i];
      const float4 c = in41[i];
      float* r_ = pA + (y + 1) * LCOLS + x4;
      float* v_ = pB + (y + 1) * LCOLS + x4;
      r_[1] = a.x; r_[2] = a.y; r_[3] = a.z; r_[4] = a.w;
      v_[1] = c.x; v_[2] = c.y; v_[3] = c.z; v_[4] = c.w;
    }
  }
  __syncthreads();

  // ---- r = conv(input, W_eff, pad=1) + b_eff ----
  {
    const float* rp = pA + nb_base;
    const float* vp = pB + nb_base;
    v2f rw[3][3], vw[3][3], racc[4][2];
    LOAD_PROW(rp, 0, rw[0]) LOAD_PROW(rp, 1, rw[1]) LOAD_PROW(rp, 2, rw[2])
    LOAD_PROW(vp, 0, vw[0]) LOAD_PROW(vp, 1, vw[1]) LOAD_PROW(vp, 2, vw[2])
    const float beff = w_eff[18];
    R_ROW(0) WIN_SHIFT2(3) R_ROW(1) WIN_SHIFT2(4) R_ROW(2) WIN_SHIFT2(5) R_ROW(3)
    __syncthreads();  // all staged-input reads done
    // pA <- r (read by qr-phase), pB <- 0 (v starts at zero; it=0 reads pB)
#pragma unroll
    for (int dy = 0; dy < 4; ++dy) {
      float* r_ = pA + wrow0 + dy * LCOLS;
      float* v_ = pB + wrow0 + dy * LCOLS;
      r_[1] = racc[dy][0].x; r_[2] = racc[dy][0].y;
      r_[3] = racc[dy][1].x; r_[4] = racc[dy][1].y;
      v_[1] = 0.0f; v_[2] = 0.0f; v_[3] = 0.0f; v_[4] = 0.0f;
    }
  }
  __syncthreads();  // r plane visible to qr-phase windows

  // ---- qr[c] = conv(r, q_w[c]) -> fp16 global (write once) ----
  {
    const float* rp = pA + nb_base;
    v2f rE[3][3], rO[3][2];
    LOADR2(0, 0) LOADR2(1, 1) LOADR2(2, 2)
    QRH_ROW(0, 0, 1, 2)
    LOADR2(0, 3) QRH_ROW(1, 1, 2, 0)
    LOADR2(1, 4) QRH_ROW(2, 2, 0, 1)
    LOADR2(2, 5) QRH_ROW(3, 0, 1, 2)
  }
  __syncthreads();  // qr stores drained (barrier waitcnt); r reads done

  // initial prefetch: row 0's 10 channel entries
  h4 qb[10];
  PREQ(0) PREQ(1) PREQ(2) PREQ(3) PREQ(4)
  PREQ(5) PREQ(6) PREQ(7) PREQ(8) PREQ(9)

  // ---- 40 VI iterations, ONE barrier each ----
  // it even: read pB, write pA; it odd: read pA, write pB -> final v in pB.
  // it=0 (v==0) yields exactly v0 = max_c qr[c] (fp16-rounded, consistent).
  // Each channel consumes qb[c] then prefetches the next row's entry:
  // load-use distance ~ one full row of compute (~500+ cyc).
#pragma unroll 1
  for (int it = 0; it < KIT; ++it) {
    const float* vp = lds + ((it & 1) ? 0 : PLANE) + nb_base;
    float* wr = lds + ((it & 1) ? PLANE : 0) + wrow0;
    v2f vE[3][3], vO[3][2];
    LOADV(0, 0) LOADV(1, 1) LOADV(2, 2)
    VI_OUT_QH(0, 1, 0, 1, 2)
    LOADV(0, 3) VI_OUT_QH(1, 2, 1, 2, 0)
    LOADV(1, 4) VI_OUT_QH(2, 3, 2, 0, 1)
    LOADV(2, 5) VI_OUT_QH(3, 0, 0, 1, 2)  // row 3 prefetches next iter's row 0
    __syncthreads();  // write-plane visible; next iter swaps planes
  }

  // ---- epilogue: q at (sx,sy) = qr + conv(v,w); logits = fc_w @ q ----
  if (tid == 0) {
    const int sx = coords[b * 4 + 0];
    const int sy = coords[b * 4 + 1];
    const int tidp = ((sx >> 2) << 5) | (sy >> 2);  // owner thread of (sx,sy)
    const int dyp = sx & 3, pxp = sy & 3;
    float qv[LQ];
#pragma unroll 1
    for (int c = 0; c < LQ; ++c) {
      const h4 hq = qrh[(c * 4 + dyp) * 1024 + tidp];
      const float q4[4] = {(float)hq.x, (float)hq.y, (float)hq.z, (float)hq.w};
      float s = q4[pxp];
#pragma unroll
      for (int kk = 0; kk < 9; ++kk) {
        const int ky = kk / 3, kx = kk % 3;
        s = __builtin_fmaf(w_in[c * 9 + kk],
                           pB[(sx + ky) * LCOLS + (sy + kx)], s);
      }
      qv[c] = s;
    }
#pragma unroll 1
    for (int a = 0; a < AOUT; ++a) {
      float s = 0.0f;
#pragma unroll
      for (int c = 0; c < LQ; ++c)
        s = __builtin_fmaf(fc_w[a * LQ + c], qv[c], s);
      out[b * AOUT + a] = s;
    }
  }
}

// ---------------- Fallback: round-10 kernel (proven 642 us), used if ws
// can't hold fp16 qr. ----------------
#define LOADR(SLOT, R)                                                       \
  {                                                                          \
    const float4 b_ = *reinterpret_cast<const float4*>(rp + (R) * LCOLS);    \
    const float2 c_ = *reinterpret_cast<const float2*>(rp + (R) * LCOLS + 4); \
    rP[SLOT][0] = (v2f){b_.x, b_.y};                                         \
    rP[SLOT][1] = (v2f){b_.z, b_.w};                                         \
    rP[SLOT][2] = (v2f){c_.x, c_.y};                                         \
  }

#define TAP_R(SLOT, K0, K1, K2)                                              \
    a0 = FMA2(SPLAT(K0), rP[SLOT][0], a0);                                   \
    a1 = FMA2(SPLAT(K0), rP[SLOT][1], a1);                                   \
    a0.x = __builtin_fmaf((K1), rP[SLOT][0].y, a0.x);                        \
    a0.y = __builtin_fmaf((K1), rP[SLOT][1].x, a0.y);                        \
    a1.x = __builtin_fmaf((K1), rP[SLOT][1].y, a1.x);                        \
    a1.y = __builtin_fmaf((K1), rP[SLOT][2].x, a1.y);                        \
    a0 = FMA2(SPLAT(K2), rP[SLOT][1], a0);                                   \
    a1 = FMA2(SPLAT(K2), rP[SLOT][2], a1);

#define VI_CH3(QC, WC, SA, SB, SC, MERGE)                                    \
  {                                                                          \
    const float* qc = (QC);                                                  \
    const float* wc = (WC);                                                  \
    v2f a0 = SPLAT(qc[0]) * rP[SA][0];                                       \
    v2f a1 = SPLAT(qc[0]) * rP[SA][1];                                       \
    a0.x = __builtin_fmaf(qc[1], rP[SA][0].y, a0.x);                         \
    a0.y = __builtin_fmaf(qc[1], rP[SA][1].x, a0.y);                         \
    a1.x = __builtin_fmaf(qc[1], rP[SA][1].y, a1.x);                         \
    a1.y = __builtin_fmaf(qc[1], rP[SA][2].x, a1.y);                         \
    a0 = FMA2(SPLAT(qc[2]), rP[SA][1], a0);                                  \
    a1 = FMA2(SPLAT(qc[2]), rP[SA][2], a1);                                  \
    TAP_R(SB, qc[3], qc[4], qc[5])                                           \
    TAP_R(SC, qc[6], qc[7], qc[8])                                           \
    TAP_V(SA, wc[0], wc[1], wc[2])                                           \
    TAP_V(SB, wc[3], wc[4], wc[5])                                           \
    TAP_V(SC, wc[6], wc[7], wc[8])                                           \
    MERGE                                                                    \
  }

#define VI_OUT(DY, SA, SB, SC)                                               \
  {                                                                          \
    v2f o0, o1;                                                              \
    VI_CH3(q_w, w_in, SA, SB, SC, o0 = a0; o1 = a1;)                         \
    _Pragma("unroll 3")                                                      \
    for (int c = 1; c < LQ; ++c) {                                           \
      VI_CH3(q_w + c * 9, w_in + c * 9, SA, SB, SC, MAXM)                    \
    }                                                                        \
    float* w_ = wr + (DY) * LCOLS;                                           \
    w_[1] = o0.x; w_[2] = o0.y; w_[3] = o1.x; w_[4] = o1.y;                  \
  }

__global__ __launch_bounds__(1024)
__attribute__((amdgpu_waves_per_eu(4, 4)))
void vin_gr(const float* __restrict__ input,
            const int* __restrict__ coords,
            const float* __restrict__ q_w,
            const float* __restrict__ w_in,
            const float* __restrict__ fc_w,
            float* __restrict__ ws,
            float* __restrict__ out) {
  extern __shared__ float lds[];
  float* pA = lds;
  float* pB = lds + PLANE;
  const float* w_eff = ws;
  float* g_r = ws + WSOFF + (size_t)blockIdx.x * PLANE;

  const int b = blockIdx.x;
  const int tid = threadIdx.x;
  const int ty = tid >> 5;
  const int tx = tid & 31;
  const int y0 = ty << 2;
  const int x0 = tx << 2;
  const int nb_base = y0 * LCOLS + x0;
  const int wrow0 = (y0 + 1) * LCOLS + x0;

  for (int i = tid; i < LDS_DWORDS; i += 1024) lds[i] = 0.0f;
  if (tid < LCOLS) { g_r[tid] = 0.0f; g_r[129 * LCOLS + tid] = 0.0f; }
  if (tid >= 256 && tid < 384) {
    const int row = tid - 255;
    g_r[row * LCOLS + 0] = 0.0f;
    g_r[row * LCOLS + 129] = 0.0f;
    g_r[row * LCOLS + 130] = 0.0f;
    g_r[row * LCOLS + 131] = 0.0f;
  }
  __syncthreads();

  const float* in0 = input + (size_t)b * (LI * HS * WSD);
  const float* in1 = in0 + HS * WSD;
  {
    const float4* in40 = (const float4*)in0;
    const float4* in41 = (const float4*)in1;
    for (int i = tid; i < HS * WSD / 4; i += 1024) {
      const int y = i >> 5, x4 = (i & 31) << 2;
      const float4 a = in40[i];
      const float4 c = in41[i];
      float* r_ = pA + (y + 1) * LCOLS + x4;
      float* v_ = pB + (y + 1) * LCOLS + x4;
      r_[1] = a.x; r_[2] = a.y; r_[3] = a.z; r_[4] = a.w;
      v_[1] = c.x; v_[2] = c.y; v_[3] = c.z; v_[4] = c.w;
    }
  }
  __syncthreads();

  {
    const float* rp = pA + nb_base;
    const float* vp = pB + nb_base;
    v2f rw[3][3], vw[3][3], racc[4][2];
    LOAD_PROW(rp, 0, rw[0]) LOAD_PROW(rp, 1, rw[1]) LOAD_PROW(rp, 2, rw[2])
    LOAD_PROW(vp, 0, vw[0]) LOAD_PROW(vp, 1, vw[1]) LOAD_PROW(vp, 2, vw[2])
    const float beff = w_eff[18];
    R_ROW(0) WIN_SHIFT2(3) R_ROW(1) WIN_SHIFT2(4) R_ROW(2) WIN_SHIFT2(5) R_ROW(3)
    __syncthreads();
#pragma unroll
    for (int dy = 0; dy < 4; ++dy) {
      float* g_ = g_r + wrow0 + dy * LCOLS;
      float* v_ = pA + wrow0 + dy * LCOLS;
      g_[1] = racc[dy][0].x; g_[2] = racc[dy][0].y;
      g_[3] = racc[dy][1].x; g_[4] = racc[dy][1].y;
      v_[1] = 0.0f; v_[2] = 0.0f; v_[3] = 0.0f; v_[4] = 0.0f;
    }
  }
  __syncthreads();

  const float* grp = g_r + nb_base;
#pragma unroll 1
  for (int it = 0; it < KIT; ++it) {
    const float* vp = lds + ((it & 1) ? PLANE : 0) + nb_base;
    float* wr = lds + ((it & 1) ? 0 : PLANE) + wrow0;
    const float* rp = grp;
    v2f rP[3][3], vE[3][3], vO[3][2];
    LOADR(0, 0) LOADR(1, 1) LOADR(2, 2)
    LOADV(0, 0) LOADV(1, 1) LOADV(2, 2)
    VI_OUT(0, 0, 1, 2)
    LOADR(0, 3) LOADV(0, 3)
    VI_OUT(1, 1, 2, 0)
    LOADR(1, 4) LOADV(1, 4)
    VI_OUT(2, 2, 0, 1)
    LOADR(2, 5) LOADV(2, 5)
    VI_OUT(3, 0, 1, 2)
    __syncthreads();
  }

  if (tid == 0) {
    const int sx = coords[b * 4 + 0];
    const int sy = coords[b * 4 + 1];
    float qv[LQ];
#pragma unroll 1
    for (int c = 0; c < LQ; ++c) {
      float s = 0.0f;
#pragma unroll
      for (int kk = 0; kk < 9; ++kk) {
        const int ky = kk / 3, kx = kk % 3;
        const int off = (sx + ky) * LCOLS + (sy + kx);
        s = __builtin_fmaf(q_w[c * 9 + kk], g_r[off],
            __builtin_fmaf(w_in[c * 9 + kk], pA[off], s));
      }
      qv[c] = s;
    }
#pragma unroll 1
    for (int a = 0; a < AOUT; ++a) {
      float s = 0.0f;
#pragma unroll
      for (int c = 0; c < LQ; ++c)
        s = __builtin_fmaf(fc_w[a * LQ + c], qv[c], s);
      out[b * AOUT + a] = s;
    }
  }
}

extern "C" void kernel_launch(void* const* d_in, const int* in_sizes, int n_in,
                              void* d_out, int out_size, void* d_ws, size_t ws_size,
                              hipStream_t stream) {
  const float* input = (const float*)d_in[0];   // (B, 2, 128, 128)
  const int*   coords = (const int*)d_in[1];    // (B, 4)
  const float* h_w = (const float*)d_in[2];     // (150, 2, 3, 3)
  const float* h_b = (const float*)d_in[3];     // (150,)
  const float* r_w = (const float*)d_in[4];     // (1, 150, 1, 1)
  const float* q_w = (const float*)d_in[5];     // (10, 1, 3, 3)
  const float* w_in = (const float*)d_in[6];    // (10, 1, 3, 3)
  const float* fc_w = (const float*)d_in[7];    // (5, 10)
  float* out = (float*)d_out;                   // (B, 5)
  float* ws = (float*)d_ws;

  const size_t smem = (size_t)LDS_DWORDS * sizeof(float);  // 137,280 B

  prep_weff<<<1, 64, 0, stream>>>(h_w, h_b, r_w, ws);

  if (ws_size >= WS_QRH_BYTES) {
    hipFuncSetAttribute(reinterpret_cast<const void*>(vin_qrh),
                        hipFuncAttributeMaxDynamicSharedMemorySize, (int)smem);
    vin_qrh<<<NBATCH, 1024, smem, stream>>>(input, coords, q_w, w_in, fc_w, ws, out);
  } else {
    hipFuncSetAttribute(reinterpret_cast<const void*>(vin_gr),
                        hipFuncAttributeMaxDynamicSharedMemorySize, (int)smem);
    vin_gr<<<NBATCH, 1024, smem, stream>>>(input, coords, q_w, w_in, fc_w, ws, out);
  }
}